// Round 5
// baseline (362.527 us; speedup 1.0000x reference)
//
#include <hip/hip_runtime.h>
#include <math.h>

#define B_    16
#define C_    256
#define NPIX  4096      // H*W
#define K_    4
#define HID_  512
#define ITERS_ 3
#define NROWS (B_*NPIX) // 65536
#define EPS_  1e-8f

__device__ __forceinline__ float gelu_f(float x) {
    return 0.5f * x * (1.0f + erff(x * 0.70710678118654752f));
}

__device__ __forceinline__ unsigned short f2bf(float x) {
    union { float f; unsigned u; } v; v.f = x;
    unsigned r = v.u + 0x7fffu + ((v.u >> 16) & 1u);   // round-nearest-even
    return (unsigned short)(r >> 16);
}
__device__ __forceinline__ float bflo(unsigned u) {
    union { unsigned u; float f; } v; v.u = u << 16; return v.f;
}
__device__ __forceinline__ float bfhi(unsigned u) {
    union { unsigned u; float f; } v; v.u = u & 0xffff0000u; return v.f;
}
__device__ __forceinline__ float4 shfl_xor4(float4 v, int m) {
    v.x = __shfl_xor(v.x, m); v.y = __shfl_xor(v.y, m);
    v.z = __shfl_xor(v.z, m); v.w = __shfl_xor(v.w, m);
    return v;
}
__device__ __forceinline__ void fma4(float4& a, const float4 w, const float4 s) {
    a.x = fmaf(w.x, s.x, a.x); a.y = fmaf(w.y, s.y, a.y);
    a.z = fmaf(w.z, s.z, a.z); a.w = fmaf(w.w, s.w, a.w);
}
__device__ __forceinline__ float hsum4(const float4 a) {
    return (a.x + a.y) + (a.z + a.w);
}

// 256-thread block: reduce (a,b) over all threads. One internal barrier;
// caller must barrier before r8 is written again.
__device__ __forceinline__ void redpair256t(float a, float b, int t, float* r8,
                                            float& o1, float& o2) {
    #pragma unroll
    for (int m = 1; m <= 32; m <<= 1) { a += __shfl_xor(a, m); b += __shfl_xor(b, m); }
    if ((t & 63) == 0) { r8[(t >> 6) * 2] = a; r8[(t >> 6) * 2 + 1] = b; }
    __syncthreads();
    o1 = r8[0] + r8[2] + r8[4] + r8[6];
    o2 = r8[1] + r8[3] + r8[5] + r8[7];
}

// ---------------- prep (merged pack + compose): 609 blocks ----------------
// blocks [0,353): pack; block 352: wqoff; blocks [353,609): compose row d.
__global__ __launch_bounds__(256) void prep_all_kernel(
    const float* __restrict__ Wu, const float* __restrict__ W1,
    const float* __restrict__ W2, const float* __restrict__ We1,
    const float* __restrict__ Wq, const float* __restrict__ Wk,
    const float* __restrict__ Wv,
    const float* __restrict__ bk, const float* __restrict__ bq,
    const float* __restrict__ bv,
    float4* __restrict__ WuC4, float4* __restrict__ W14,
    float4* __restrict__ W24, float4* __restrict__ We14,
    float4* __restrict__ Wqk4,
    float* __restrict__ bv2, float* __restrict__ bqk, float* __restrict__ wqoff) {
    const int role = blockIdx.x;
    if (role < 353) {
        __shared__ float r4[4];
        if (role == 352) {        // wqoff + bqoff
            int c = threadIdx.x;
            float s = 0.f;
            for (int dd = 0; dd < 256; ++dd) s = fmaf(Wq[dd * 256 + c], bk[dd], s);
            wqoff[c] = s;
            float p = bq[c] * bk[c];
            #pragma unroll
            for (int m = 1; m <= 32; m <<= 1) p += __shfl_xor(p, m);
            if ((c & 63) == 0) r4[c >> 6] = p;
            __syncthreads();
            if (c == 0) wqoff[256] = r4[0] + r4[1] + r4[2] + r4[3];
            return;
        }
        int i = role * 256 + threadIdx.x;
        if (i < 16384) {
            int c4 = i >> 8, dd = i & 255;
            WuC4[i] = *(const float4*)&Wu[dd * 512 + c4 * 4];      // left half
        } else if (i < 49152) {
            int j = i - 16384; int c4 = j >> 9, h = j & 511;
            W14[j] = *(const float4*)&W1[h * 256 + c4 * 4];
        } else if (i < 81920) {
            int j = i - 49152; int h4 = j >> 8, dd = j & 255;
            W24[j] = *(const float4*)&W2[dd * 512 + h4 * 4];
        } else {
            int j = i - 81920; int c4 = j >> 7, e = j & 127;
            We14[j] = *(const float4*)&We1[e * 256 + c4 * 4];
        }
        return;
    }
    // compose: Wuv[d][*] = Wu_right[d] . Wv ; Wqk[d][*] = Wk^T[d] . Wq
    __shared__ float wur[256], wkc[256];
    __shared__ float ldsA[256], ldsB[256];
    __shared__ float r1[4], r2[4];
    const int d = role - 353, c = threadIdx.x;
    wur[c] = Wu[d * 512 + 256 + c];
    wkc[c] = Wk[c * 256 + d];
    __syncthreads();
    float a = 0.f, b = 0.f;
    #pragma unroll 4
    for (int e = 0; e < 256; ++e) {
        a = fmaf(wur[e], Wv[e * 256 + c], a);
        b = fmaf(wkc[e], Wq[e * 256 + c], b);
    }
    ldsA[c] = a; ldsB[c] = b;
    float p1 = wur[c] * bv[c], p2 = wkc[c] * bq[c];
    #pragma unroll
    for (int m = 1; m <= 32; m <<= 1) { p1 += __shfl_xor(p1, m); p2 += __shfl_xor(p2, m); }
    if ((c & 63) == 0) { r1[c >> 6] = p1; r2[c >> 6] = p2; }
    __syncthreads();
    if (c < 64) {
        float4 qa = { ldsA[4 * c], ldsA[4 * c + 1], ldsA[4 * c + 2], ldsA[4 * c + 3] };
        float4 qb = { ldsB[4 * c], ldsB[4 * c + 1], ldsB[4 * c + 2], ldsB[4 * c + 3] };
        WuC4[(64 + c) * 256 + d] = qa;
        Wqk4[c * 256 + d] = qb;
    }
    if (c == 0) {
        bv2[d] = r1[0] + r1[1] + r1[2] + r1[3];
        bqk[d] = r2[0] + r2[1] + r2[2] + r2[3];
    }
}

// ---------------- fused LN + transpose + bf16, 512 threads, register stats ----------------
__global__ __launch_bounds__(512) void xn_fused_kernel(
    const float* __restrict__ x, const float* __restrict__ g, const float* __restrict__ bta,
    unsigned short* __restrict__ xnb) {
    __shared__ float tile[256][65];
    __shared__ float sg[256], sb[256];
    __shared__ float red1[512], red2[512];
    __shared__ float smean[64], srstd[64];
    const int tid = threadIdx.x;
    const int nt = blockIdx.x << 6, b = blockIdx.y;

    if (tid < 256) { sg[tid] = g[tid]; sb[tid] = bta[tid]; }
    float s = 0.f, s2 = 0.f;
    #pragma unroll
    for (int r = 0; r < 32; ++r) {
        int idx = tid + (r << 9);
        int c_l = idx >> 6, n_l = idx & 63;
        float v = x[(size_t)(b * C_ + c_l) * NPIX + nt + n_l];
        tile[c_l][n_l] = v;
        s += v; s2 += v * v;
    }
    red1[tid] = s; red2[tid] = s2;
    __syncthreads();
    if (tid < 64) {
        float a = 0.f, a2 = 0.f;
        #pragma unroll
        for (int j = 0; j < 8; ++j) { a += red1[tid + 64 * j]; a2 += red2[tid + 64 * j]; }
        float m = a * (1.0f / C_);
        smean[tid] = m;
        srstd[tid] = rsqrtf(a2 * (1.0f / C_) - m * m + 1e-5f);
    }
    __syncthreads();
    #pragma unroll
    for (int r = 0; r < 16; ++r) {
        int idx = tid + (r << 9);
        int n_l = idx >> 7, cp = idx & 127;
        int c0 = cp << 1;
        float mn = smean[n_l], rs = srstd[n_l];
        float v0 = (tile[c0][n_l] - mn) * rs * sg[c0] + sb[c0];
        float v1 = (tile[c0 + 1][n_l] - mn) * rs * sg[c0 + 1] + sb[c0 + 1];
        ushort2 o; o.x = f2bf(v0); o.y = f2bf(v1);
        *reinterpret_cast<ushort2*>(&xnb[((size_t)(b * NPIX + nt + n_l)) * C_ + c0]) = o;
    }
}

// ---------------- init + first qt: grid (2, 64) ----------------
__global__ __launch_bounds__(256) void initqt_kernel(
    const float* __restrict__ noise, const float* __restrict__ mu,
    const float* __restrict__ log_sigma,
    const float* __restrict__ g_sl, const float* __restrict__ b_sl,
    const float4* __restrict__ Wqk4, const float* __restrict__ bqk,
    const float* __restrict__ wqoff,
    float* __restrict__ slots, float* __restrict__ qtbuf, float* __restrict__ qoffbuf,
    float* __restrict__ usum0, float* __restrict__ denom0) {
    __shared__ __align__(16) float mrow[256];
    __shared__ float pq[256];
    __shared__ float r8[8];
    const int t = threadIdx.x, dq = blockIdx.x, r = blockIdx.y;
    float v = mu[t] + expf(log_sigma[t]) * noise[r * C_ + t];
    if (dq == 0) {
        slots[r * C_ + t] = v;
        usum0[r * C_ + t] = 0.f;
        if (t == 0) denom0[r] = 0.f;
    }
    float sm, s2;
    redpair256t(v, v * v, t, r8, sm, s2);
    float mean = sm * (1.f / C_);
    float rs = rsqrtf(s2 * (1.f / C_) - mean * mean + 1e-5f);
    mrow[t] = (v - mean) * rs * g_sl[t] + b_sl[t];
    __syncthreads();
    const float4* sn4 = (const float4*)mrow;
    const int dloc = t & 127, ks = t >> 7;
    const int dout = dq * 128 + dloc;
    {
        float4 a0 = {0,0,0,0}, a1 = {0,0,0,0};
        int c4b = ks << 5;
        #pragma unroll
        for (int i = 0; i < 32; i += 2) {
            fma4(a0, Wqk4[(c4b + i) * 256 + dout], sn4[c4b + i]);
            fma4(a1, Wqk4[(c4b + i + 1) * 256 + dout], sn4[c4b + i + 1]);
        }
        pq[ks * 128 + dloc] = hsum4(a0) + hsum4(a1);
    }
    __syncthreads();
    if (t < 128)
        qtbuf[r * C_ + dq * 128 + t] = pq[t] + pq[128 + t] + bqk[dq * 128 + t];
    if (dq == 0) {
        float p = mrow[t] * wqoff[t];
        #pragma unroll
        for (int m = 1; m <= 32; m <<= 1) p += __shfl_xor(p, m);
        if ((t & 63) == 0) r8[t >> 6] = p;
        __syncthreads();
        if (t == 0) qoffbuf[r] = r8[0] + r8[1] + r8[2] + r8[3] + wqoff[256];
    }
}

// ---------------- fully-fused slot update: grid (2, 64) ----------------
// Each block computes the FULL row chain redundantly, writes its 128-slice
// of dst and its 128-wide qt tile. Ping-pong slots / usum buffers (no races).
__global__ __launch_bounds__(256) void upd_full_kernel(
    const float* __restrict__ slots_in,
    const float* __restrict__ usum_cur, const float* __restrict__ denom_cur,
    float* __restrict__ usum_nxt, float* __restrict__ denom_nxt,
    const float4* __restrict__ WuC4, const float* __restrict__ bu,
    const float* __restrict__ bv2,
    const float* __restrict__ g_mlp, const float* __restrict__ b_mlp,
    const float4* __restrict__ W14, const float* __restrict__ b1,
    const float4* __restrict__ W24, const float* __restrict__ b2,
    const float* __restrict__ g_sl, const float* __restrict__ b_sl,
    const float4* __restrict__ Wqk4, const float* __restrict__ bqk,
    const float* __restrict__ wqoff,
    float* __restrict__ qtbuf, float* __restrict__ qoffbuf,
    float* __restrict__ dst,
    const float4* __restrict__ We14, const float* __restrict__ be1,
    const float* __restrict__ We2, const float* __restrict__ be2,
    float* __restrict__ out, int final_it) {
    __shared__ __align__(16) float comb[512];   // [prev|u'] then hrow
    __shared__ __align__(16) float mrow[256];
    __shared__ float pq[256];
    __shared__ float erow[128];
    __shared__ float r8[8];
    __shared__ float sden, sscale;
    const int t = threadIdx.x, dq = blockIdx.x, r = blockIdx.y;

    // phase A: gather row state; zero next-iteration accumulators (different buffer)
    float prev = slots_in[r * C_ + t];
    float uv = usum_cur[r * C_ + t];
    if (!final_it && dq == 0) {
        usum_nxt[r * C_ + t] = 0.f;
        if (t == 0) denom_nxt[r] = 0.f;
    }
    if (t == 0) { float dv = denom_cur[r]; sden = dv + EPS_; sscale = dv / (dv + EPS_); }
    comb[t] = prev;
    __syncthreads();
    comb[256 + t] = uv / sden;
    __syncthreads();
    // phase B: full nv = [WuL|Wuv].comb + bu + prev + scale*bv2   (d = t)
    float nv;
    {
        const float4* cb4 = (const float4*)comb;
        float4 a0 = {0,0,0,0}, a1 = {0,0,0,0};
        #pragma unroll 8
        for (int c4 = 0; c4 < 128; c4 += 2) {
            fma4(a0, WuC4[c4 * 256 + t], cb4[c4]);
            fma4(a1, WuC4[(c4 + 1) * 256 + t], cb4[c4 + 1]);
        }
        nv = hsum4(a0) + hsum4(a1) + bu[t] + prev + sscale * bv2[t];
    }
    // phase C: LN_mlp(nv) -> mrow
    {
        float sm, s2;
        redpair256t(nv, nv * nv, t, r8, sm, s2);
        float mean = sm * (1.f / C_);
        float rs = rsqrtf(s2 * (1.f / C_) - mean * mean + 1e-5f);
        mrow[t] = (nv - mean) * rs * g_mlp[t] + b_mlp[t];
    }
    __syncthreads();
    // phase D: full h = gelu(W1.mrow + b1); 2 outputs/thread -> comb (hrow)
    {
        const float4* m4 = (const float4*)mrow;
        float4 a0 = {0,0,0,0}, a1 = {0,0,0,0}, a2 = {0,0,0,0}, a3 = {0,0,0,0};
        #pragma unroll 4
        for (int c4 = 0; c4 < 64; c4 += 2) {
            float4 s0 = m4[c4], s1 = m4[c4 + 1];
            fma4(a0, W14[c4 * 512 + t], s0);
            fma4(a1, W14[(c4 + 1) * 512 + t], s1);
            fma4(a2, W14[c4 * 512 + t + 256], s0);
            fma4(a3, W14[(c4 + 1) * 512 + t + 256], s1);
        }
        float h0 = gelu_f(hsum4(a0) + hsum4(a1) + b1[t]);
        float h1 = gelu_f(hsum4(a2) + hsum4(a3) + b1[t + 256]);
        __syncthreads();            // everyone done reading comb as [prev|u']? (B done) + mrow ready
        comb[t] = h0; comb[256 + t] = h1;
    }
    __syncthreads();
    // phase E: full ov = nv + W2.h + b2   (d = t); write my 128-slice
    float ov;
    {
        const float4* h4 = (const float4*)comb;
        float4 a0 = {0,0,0,0}, a1 = {0,0,0,0};
        #pragma unroll 8
        for (int h4i = 0; h4i < 128; h4i += 2) {
            fma4(a0, W24[h4i * 256 + t], h4[h4i]);
            fma4(a1, W24[(h4i + 1) * 256 + t], h4[h4i + 1]);
        }
        ov = nv + hsum4(a0) + hsum4(a1) + b2[t];
    }
    if ((t >> 7) == dq) dst[r * C_ + t] = ov;
    if (!final_it) {
        // phase F: LN_sl(ov) + qt tile (128 wide) + qoff (dq==0)
        float sm, s2;
        redpair256t(ov, ov * ov, t, r8, sm, s2);
        float mean = sm * (1.f / C_);
        float rs = rsqrtf(s2 * (1.f / C_) - mean * mean + 1e-5f);
        mrow[t] = (ov - mean) * rs * g_sl[t] + b_sl[t];
        __syncthreads();
        const float4* sn4 = (const float4*)mrow;
        const int dloc = t & 127, ks = t >> 7;
        const int dout = dq * 128 + dloc;
        {
            float4 a0 = {0,0,0,0}, a1 = {0,0,0,0};
            int c4b = ks << 5;
            #pragma unroll
            for (int i = 0; i < 32; i += 2) {
                fma4(a0, Wqk4[(c4b + i) * 256 + dout], sn4[c4b + i]);
                fma4(a1, Wqk4[(c4b + i + 1) * 256 + dout], sn4[c4b + i + 1]);
            }
            pq[ks * 128 + dloc] = hsum4(a0) + hsum4(a1);
        }
        __syncthreads();
        if (t < 128)
            qtbuf[r * C_ + dq * 128 + t] = pq[t] + pq[128 + t] + bqk[dq * 128 + t];
        if (dq == 0) {
            float p = mrow[t] * wqoff[t];
            #pragma unroll
            for (int m = 1; m <= 32; m <<= 1) p += __shfl_xor(p, m);
            if ((t & 63) == 0) r8[t >> 6] = p;
            __syncthreads();
            if (t == 0) qoffbuf[r] = r8[0] + r8[1] + r8[2] + r8[3] + wqoff[256];
        }
    } else if (dq == 0) {
        // head: e = gelu(We1.ov + be1); out_w = sigmoid(We2.e + be2)
        mrow[t] = ov;
        __syncthreads();
        const float4* m4 = (const float4*)mrow;
        const int e = t & 127, o2 = t >> 7;
        {
            float4 a0 = {0,0,0,0}, a1 = {0,0,0,0};
            int c4b = o2 << 5;
            #pragma unroll
            for (int i = 0; i < 32; i += 2) {
                fma4(a0, We14[(c4b + i) * 128 + e], m4[c4b + i]);
                fma4(a1, We14[(c4b + i + 1) * 128 + e], m4[c4b + i + 1]);
            }
            pq[o2 * 128 + e] = hsum4(a0) + hsum4(a1);
        }
        __syncthreads();
        if (t < 128) erow[t] = gelu_f(pq[t] + pq[128 + t] + be1[t]);
        __syncthreads();
        if (t < 64) {
            float p = We2[t] * erow[t] + We2[t + 64] * erow[t + 64];
            #pragma unroll
            for (int m = 1; m <= 32; m <<= 1) p += __shfl_xor(p, m);
            if (t == 0) r8[0] = p;
        }
        __syncthreads();
        if (t == 0) out[B_ * K_ * C_ + r] = 1.0f / (1.0f + expf(-(r8[0] + be2[0])));
    }
}

// ---------------- fused attention: 128 pixels per block, grid (32, 16) ----------------
__global__ __launch_bounds__(256) void attn_fused_kernel(
    const float* __restrict__ qtbuf, const float* __restrict__ qoffbuf,
    const unsigned short* __restrict__ xnb,
    float* __restrict__ usum, float* __restrict__ denom) {
    __shared__ float4 qT[264];
    __shared__ float attns[K_][64];
    __shared__ float upd_s[K_][256];
    __shared__ float asw[4][4];
    __shared__ float4 qo_s;

    const int tid = threadIdx.x;
    const int b = blockIdx.y;
    const int n0 = blockIdx.x << 7;
    const int wave = tid >> 6, lane = tid & 63;

    {
        int c = tid;
        float4 qv;
        qv.x = qtbuf[b * 1024 + c];
        qv.y = qtbuf[b * 1024 + 256 + c];
        qv.z = qtbuf[b * 1024 + 512 + c];
        qv.w = qtbuf[b * 1024 + 768 + c];
        qT[c + (c >> 5)] = qv;
        if (tid == 0) qo_s = *(const float4*)&qoffbuf[b * 4];
    }
    __syncthreads();

    const int cpart = tid & 7;
    const int npair = tid >> 3;
    const int c0 = cpart << 5;
    const int h = wave >> 1;
    const int vc = ((wave & 1) << 7) + lane * 2;
    float va0[K_] = {0.f, 0.f, 0.f, 0.f};
    float va1[K_] = {0.f, 0.f, 0.f, 0.f};
    float4 wacc = {0.f, 0.f, 0.f, 0.f};

    for (int sc = 0; sc < 2; ++sc) {
        const int nb = n0 + (sc << 6);
        float4 acc0 = {0.f, 0.f, 0.f, 0.f}, acc1 = {0.f, 0.f, 0.f, 0.f};
        const unsigned short* kbase = xnb + ((size_t)b * NPIX + nb + npair * 2) * C_ + c0;
        #pragma unroll
        for (int j = 0; j < 4; ++j) {
            uint4 k0 = *reinterpret_cast<const uint4*>(kbase + j * 8);
            uint4 k1 = *reinterpret_cast<const uint4*>(kbase + C_ + j * 8);
            const unsigned kw0[4] = {k0.x, k0.y, k0.z, k0.w};
            const unsigned kw1[4] = {k1.x, k1.y, k1.z, k1.w};
            #pragma unroll
            for (int jj = 0; jj < 4; ++jj) {
                int cidx = c0 + j * 8 + jj * 2 + cpart;
                float4 qa = qT[cidx];
                float4 qb = qT[cidx + 1];
                float f00 = bflo(kw0[jj]), f01 = bfhi(kw0[jj]);
                float f10 = bflo(kw1[jj]), f11 = bfhi(kw1[jj]);
                acc0.x += f00 * qa.x + f01 * qb.x;  acc0.y += f00 * qa.y + f01 * qb.y;
                acc0.z += f00 * qa.z + f01 * qb.z;  acc0.w += f00 * qa.w + f01 * qb.w;
                acc1.x += f10 * qa.x + f11 * qb.x;  acc1.y += f10 * qa.y + f11 * qb.y;
                acc1.z += f10 * qa.z + f11 * qb.z;  acc1.w += f10 * qa.w + f11 * qb.w;
            }
        }
        #pragma unroll
        for (int m = 1; m <= 4; m <<= 1) {
            acc0 = acc0 + shfl_xor4(acc0, m);
            acc1 = acc1 + shfl_xor4(acc1, m);
        }
        float4 w0, w1;
        {
            float4 l = (acc0 + qo_s) * 0.0625f;
            float mx = fmaxf(fmaxf(l.x, l.y), fmaxf(l.z, l.w));
            w0.x = expf(l.x - mx); w0.y = expf(l.y - mx);
            w0.z = expf(l.z - mx); w0.w = expf(l.w - mx);
            float inv = 1.0f / (w0.x + w0.y + w0.z + w0.w);
            w0 = w0 * inv;
            l = (acc1 + qo_s) * 0.0625f;
            mx = fmaxf(fmaxf(l.x, l.y), fmaxf(l.z, l.w));
            w1.x = expf(l.x - mx); w1.y = expf(l.y - mx);
            w1.z = expf(l.z - mx); w1.w = expf(l.w - mx);
            inv = 1.0f / (w1.x + w1.y + w1.z + w1.w);
            w1 = w1 * inv;
        }
        if (cpart == 0) {
            int n_l = npair * 2;
            attns[0][n_l] = w0.x; attns[1][n_l] = w0.y;
            attns[2][n_l] = w0.z; attns[3][n_l] = w0.w;
            attns[0][n_l + 1] = w1.x; attns[1][n_l + 1] = w1.y;
            attns[2][n_l + 1] = w1.z; attns[3][n_l + 1] = w1.w;
        }
        wacc = wacc + w0 + w1;
        __syncthreads();
        // V phase for this 64-pixel sub-chunk
        const unsigned short* vbase = xnb + ((size_t)b * NPIX + nb + h * 32) * C_ + vc;
        #pragma unroll 4
        for (int nn = 0; nn < 32; ++nn) {
            unsigned vv = *reinterpret_cast<const unsigned*>(vbase + (size_t)nn * C_);
            float v0 = bflo(vv), v1 = bfhi(vv);
            int n_l = h * 32 + nn;
            float q0 = attns[0][n_l], q1 = attns[1][n_l];
            float q2 = attns[2][n_l], q3 = attns[3][n_l];
            va0[0] = fmaf(q0, v0, va0[0]); va1[0] = fmaf(q0, v1, va1[0]);
            va0[1] = fmaf(q1, v0, va0[1]); va1[1] = fmaf(q1, v1, va1[1]);
            va0[2] = fmaf(q2, v0, va0[2]); va1[2] = fmaf(q2, v1, va1[2]);
            va0[3] = fmaf(q3, v0, va0[3]); va1[3] = fmaf(q3, v1, va1[3]);
        }
        __syncthreads();   // attns consumed; next sc may overwrite
    }
    #pragma unroll
    for (int m = 8; m <= 32; m <<= 1) wacc = wacc + shfl_xor4(wacc, m);
    if (lane == 0) {
        asw[wave][0] = wacc.x; asw[wave][1] = wacc.y;
        asw[wave][2] = wacc.z; asw[wave][3] = wacc.w;
    }
    __syncthreads();
    if (tid < 4)
        atomicAdd(&denom[b * 4 + tid],
                  asw[0][tid] + asw[1][tid] + asw[2][tid] + asw[3][tid]);
    if (h == 0) {
        #pragma unroll
        for (int k = 0; k < K_; ++k) { upd_s[k][vc] = va0[k]; upd_s[k][vc + 1] = va1[k]; }
    }
    __syncthreads();
    if (h == 1) {
        #pragma unroll
        for (int k = 0; k < K_; ++k) { upd_s[k][vc] += va0[k]; upd_s[k][vc + 1] += va1[k]; }
    }
    __syncthreads();
    #pragma unroll
    for (int k = 0; k < K_; ++k)
        atomicAdd(&usum[((size_t)b * K_ + k) * 256 + tid], upd_s[k][tid]);
}

extern "C" void kernel_launch(void* const* d_in, const int* in_sizes, int n_in,
                              void* d_out, int out_size, void* d_ws, size_t ws_size,
                              hipStream_t stream) {
    (void)in_sizes; (void)n_in; (void)out_size; (void)ws_size;
    const float* x        = (const float*)d_in[0];
    const float* noise    = (const float*)d_in[1];
    const float* slot_mu  = (const float*)d_in[2];
    const float* slot_ls  = (const float*)d_in[3];
    const float* ln_in_g  = (const float*)d_in[4];
    const float* ln_in_b  = (const float*)d_in[5];
    const float* ln_sl_g  = (const float*)d_in[6];
    const float* ln_sl_b  = (const float*)d_in[7];
    const float* ln_mlp_g = (const float*)d_in[8];
    const float* ln_mlp_b = (const float*)d_in[9];
    const float* Wq = (const float*)d_in[10];
    const float* bq = (const float*)d_in[11];
    const float* Wk = (const float*)d_in[12];
    const float* bk = (const float*)d_in[13];
    const float* Wv = (const float*)d_in[14];
    const float* bv = (const float*)d_in[15];
    const float* Wu = (const float*)d_in[16];
    const float* bu = (const float*)d_in[17];
    const float* W1 = (const float*)d_in[18];
    const float* b1 = (const float*)d_in[19];
    const float* W2 = (const float*)d_in[20];
    const float* b2 = (const float*)d_in[21];
    const float* We1 = (const float*)d_in[22];
    const float* be1 = (const float*)d_in[23];
    const float* We2 = (const float*)d_in[24];
    const float* be2 = (const float*)d_in[25];
    float* out = (float*)d_out;

    char* ws = (char*)d_ws;
    unsigned short* xnb = (unsigned short*)ws;                  // 32 MiB
    float4* WuC4 = (float4*)(xnb + (size_t)NROWS * C_);         // 32768 f4
    float4* W14  = WuC4 + 32768;                                // 32768 f4
    float4* W24  = W14 + 32768;                                 // 32768 f4
    float4* We14 = W24 + 32768;                                 // 8192 f4
    float4* Wqk4 = We14 + 8192;                                 // 16384 f4
    float* bv2    = (float*)(Wqk4 + 16384);                     // 256
    float* bqk    = bv2 + 256;                                  // 256
    float* wqoff  = bqk + 256;                                  // 257 (+pad)
    float* slots0 = wqoff + 260;                                // 16384
    float* slots1 = slots0 + B_ * K_ * C_;                      // 16384
    float* qtbuf  = slots1 + B_ * K_ * C_;                      // 16384
    float* qoffb  = qtbuf + B_ * K_ * C_;                       // 64
    float* usum0  = qoffb + B_ * K_;                            // 16384
    float* denom0 = usum0 + B_ * K_ * C_;                       // 64
    float* usum1  = denom0 + B_ * K_;                           // 16384
    float* denom1 = usum1 + B_ * K_ * C_;                       // 64

    prep_all_kernel<<<609, 256, 0, stream>>>(Wu, W1, W2, We1, Wq, Wk, Wv, bk, bq, bv,
                                             WuC4, W14, W24, We14, Wqk4,
                                             bv2, bqk, wqoff);
    xn_fused_kernel<<<dim3(64, 16), 512, 0, stream>>>(x, ln_in_g, ln_in_b, xnb);
    initqt_kernel<<<dim3(2, B_ * K_), 256, 0, stream>>>(noise, slot_mu, slot_ls,
                                                        ln_sl_g, ln_sl_b, Wqk4, bqk, wqoff,
                                                        slots0, qtbuf, qoffb, usum0, denom0);
    for (int it = 0; it < ITERS_; ++it) {
        const int fin = (it == ITERS_ - 1);
        float* usA = (it & 1) ? usum1 : usum0;
        float* dnA = (it & 1) ? denom1 : denom0;
        float* usB = (it & 1) ? usum0 : usum1;
        float* dnB = (it & 1) ? denom0 : denom1;
        const float* sin = (it & 1) ? slots1 : slots0;
        float* sout = fin ? out : ((it & 1) ? slots0 : slots1);
        attn_fused_kernel<<<dim3(32, 16), 256, 0, stream>>>(qtbuf, qoffb, xnb, usA, dnA);
        upd_full_kernel<<<dim3(2, B_ * K_), 256, 0, stream>>>(
            sin, usA, dnA, usB, dnB,
            WuC4, bu, bv2, ln_mlp_g, ln_mlp_b, W14, b1, W24, b2,
            ln_sl_g, ln_sl_b, Wqk4, bqk, wqoff, qtbuf, qoffb,
            sout, We14, be1, We2, be2, out, fin);
    }
}

// Round 6
// 301.541 us; speedup vs baseline: 1.2022x; 1.2022x over previous
//
#include <hip/hip_runtime.h>
#include <math.h>

#define B_    16
#define C_    256
#define NPIX  4096      // H*W
#define K_    4
#define HID_  512
#define ITERS_ 3
#define NROWS (B_*NPIX) // 65536
#define EPS_  1e-8f

__device__ __forceinline__ float gelu_f(float x) {
    return 0.5f * x * (1.0f + erff(x * 0.70710678118654752f));
}

__device__ __forceinline__ unsigned short f2bf(float x) {
    union { float f; unsigned u; } v; v.f = x;
    unsigned r = v.u + 0x7fffu + ((v.u >> 16) & 1u);   // round-nearest-even
    return (unsigned short)(r >> 16);
}
__device__ __forceinline__ float bflo(unsigned u) {
    union { unsigned u; float f; } v; v.u = u << 16; return v.f;
}
__device__ __forceinline__ float bfhi(unsigned u) {
    union { unsigned u; float f; } v; v.u = u & 0xffff0000u; return v.f;
}
__device__ __forceinline__ float4 shfl_xor4(float4 v, int m) {
    v.x = __shfl_xor(v.x, m); v.y = __shfl_xor(v.y, m);
    v.z = __shfl_xor(v.z, m); v.w = __shfl_xor(v.w, m);
    return v;
}
__device__ __forceinline__ void fma4(float4& a, const float4 w, const float4 s) {
    a.x = fmaf(w.x, s.x, a.x); a.y = fmaf(w.y, s.y, a.y);
    a.z = fmaf(w.z, s.z, a.z); a.w = fmaf(w.w, s.w, a.w);
}
__device__ __forceinline__ float hsum4(const float4 a) {
    return (a.x + a.y) + (a.z + a.w);
}

// ---------------- prep: packed + composed + LN-folded weights ----------------
// WuC4[c4][d] : c4<64 = Wu_left, c4 in [64,128) = Wuv = Wu_right . Wv
// W24[h4][d]  = {W2[d][4h4..]}
// W1gT[c][j]  = W1[j][c] * g_mlp[c]
// WqgT[c][d]  = Wqk[d][c] * g_sl[c],   Wqk = Wk^T . Wq
// We1T[c][e]  = We1[e][c]
// w1gsum[j] = sum_c W1[j][c]*g_mlp[c]; w1bsum[j] = sum_c W1[j][c]*b_mlp[c] + b1[j]
// wqgsum[d] = sum_c Wqk[d][c]*g_sl[c]; wqbsum[d] = sum_c Wqk[d][c]*b_sl[c] + bqk[d]
// wqg[c] = wqoff[c]*g_sl[c];  wqS[0]=sum wqoff*g_sl;  wqS[1]=sum wqoff*b_sl + bq.bk
// bv2[d] = Wu_right[d] . bv
__global__ __launch_bounds__(256) void prep_all_kernel(
    const float* __restrict__ Wu, const float* __restrict__ W1,
    const float* __restrict__ W2, const float* __restrict__ We1,
    const float* __restrict__ Wq, const float* __restrict__ Wk,
    const float* __restrict__ Wv,
    const float* __restrict__ bk, const float* __restrict__ bq,
    const float* __restrict__ bv, const float* __restrict__ b1,
    const float* __restrict__ g_sl, const float* __restrict__ b_sl,
    const float* __restrict__ g_mlp, const float* __restrict__ b_mlp,
    float4* __restrict__ WuC4, float4* __restrict__ W24,
    float* __restrict__ W1gT, float* __restrict__ WqgT,
    float* __restrict__ We1T,
    float* __restrict__ w1gsum, float* __restrict__ w1bsum,
    float* __restrict__ wqgsum, float* __restrict__ wqbsum,
    float* __restrict__ wqg, float* __restrict__ wqS,
    float* __restrict__ bv2) {
    const int role = blockIdx.x;
    const int t = threadIdx.x;
    if (role < 64) {                       // WuC left pack
        int i = role * 256 + t;
        int c4 = i >> 8, dd = i & 255;
        WuC4[i] = *(const float4*)&Wu[dd * 512 + c4 * 4];
        return;
    }
    if (role < 192) {                      // W24 pack
        int j = (role - 64) * 256 + t;
        int h4 = j >> 8, dd = j & 255;
        W24[j] = *(const float4*)&W2[dd * 512 + h4 * 4];
        return;
    }
    if (role < 704) {                      // W1gT
        int idx = (role - 192) * 256 + t;
        int c = idx & 255, jj = idx >> 8;
        W1gT[c * 512 + jj] = W1[jj * 256 + c] * g_mlp[c];
        return;
    }
    if (role < 832) {                      // We1T
        int idx = (role - 704) * 256 + t;
        int c = idx & 255, e = idx >> 8;
        We1T[c * 128 + e] = We1[e * 256 + c];
        return;
    }
    if (role == 832) {                     // wqg, wqS
        __shared__ float r12[12];
        int c = t;
        float w = 0.f;
        for (int dd = 0; dd < 256; ++dd) w = fmaf(Wq[dd * 256 + c], bk[dd], w);
        wqg[c] = w * g_sl[c];
        float pA = w * g_sl[c], pB = w * b_sl[c], pC = bq[c] * bk[c];
        #pragma unroll
        for (int m = 1; m <= 32; m <<= 1) {
            pA += __shfl_xor(pA, m); pB += __shfl_xor(pB, m); pC += __shfl_xor(pC, m);
        }
        if ((c & 63) == 0) {
            int w4 = c >> 6;
            r12[w4] = pA; r12[4 + w4] = pB; r12[8 + w4] = pC;
        }
        __syncthreads();
        if (c == 0) {
            wqS[0] = r12[0] + r12[1] + r12[2] + r12[3];
            wqS[1] = (r12[4] + r12[5] + r12[6] + r12[7])
                   + (r12[8] + r12[9] + r12[10] + r12[11]);
        }
        return;
    }
    if (role < 835) {                      // w1gsum/w1bsum (2 blocks)
        int j = (role - 833) * 256 + t;
        float sg = 0.f, sb = 0.f;
        for (int c = 0; c < 256; ++c) {
            float w = W1[j * 256 + c];
            sg = fmaf(w, g_mlp[c], sg);
            sb = fmaf(w, b_mlp[c], sb);
        }
        w1gsum[j] = sg;
        w1bsum[j] = sb + b1[j];
        return;
    }
    // compose row d: Wuv[d][*], Wqk[d][*] + folded vectors
    {
        __shared__ float wur[256], wkc[256];
        __shared__ float ldsA[256];
        __shared__ float r16[16];
        const int d = role - 835, c = t;
        wur[c] = Wu[d * 512 + 256 + c];
        wkc[c] = Wk[c * 256 + d];
        __syncthreads();
        float a = 0.f, b = 0.f;
        #pragma unroll 4
        for (int e = 0; e < 256; ++e) {
            a = fmaf(wur[e], Wv[e * 256 + c], a);     // Wuv[d][c]
            b = fmaf(wkc[e], Wq[e * 256 + c], b);     // Wqk[d][c]
        }
        ldsA[c] = a;
        WqgT[c * 256 + d] = b * g_sl[c];
        float pA = wur[c] * bv[c];     // bv2
        float pB = wkc[c] * bq[c];     // bqk
        float pC = b * g_sl[c];        // wqgsum
        float pD = b * b_sl[c];        // wqbsum partial
        #pragma unroll
        for (int m = 1; m <= 32; m <<= 1) {
            pA += __shfl_xor(pA, m); pB += __shfl_xor(pB, m);
            pC += __shfl_xor(pC, m); pD += __shfl_xor(pD, m);
        }
        if ((c & 63) == 0) {
            int w4 = c >> 6;
            r16[w4] = pA; r16[4 + w4] = pB; r16[8 + w4] = pC; r16[12 + w4] = pD;
        }
        __syncthreads();
        if (c < 64) {
            float4 qa = { ldsA[4 * c], ldsA[4 * c + 1], ldsA[4 * c + 2], ldsA[4 * c + 3] };
            WuC4[(64 + c) * 256 + d] = qa;
        }
        if (c == 0) {
            bv2[d] = r16[0] + r16[1] + r16[2] + r16[3];
            float bqk = r16[4] + r16[5] + r16[6] + r16[7];
            wqgsum[d] = r16[8] + r16[9] + r16[10] + r16[11];
            wqbsum[d] = (r16[12] + r16[13] + r16[14] + r16[15]) + bqk;
        }
    }
}

// ---------------- fused LN + transpose + bf16, 512 threads ----------------
__global__ __launch_bounds__(512) void xn_fused_kernel(
    const float* __restrict__ x, const float* __restrict__ g, const float* __restrict__ bta,
    unsigned short* __restrict__ xnb) {
    __shared__ float tile[256][65];
    __shared__ float sg[256], sb[256];
    __shared__ float red1[512], red2[512];
    __shared__ float smean[64], srstd[64];
    const int tid = threadIdx.x;
    const int nt = blockIdx.x << 6, b = blockIdx.y;

    if (tid < 256) { sg[tid] = g[tid]; sb[tid] = bta[tid]; }
    float s = 0.f, s2 = 0.f;
    #pragma unroll
    for (int r = 0; r < 32; ++r) {
        int idx = tid + (r << 9);
        int c_l = idx >> 6, n_l = idx & 63;
        float v = x[(size_t)(b * C_ + c_l) * NPIX + nt + n_l];
        tile[c_l][n_l] = v;
        s += v; s2 += v * v;
    }
    red1[tid] = s; red2[tid] = s2;
    __syncthreads();
    if (tid < 64) {
        float a = 0.f, a2 = 0.f;
        #pragma unroll
        for (int j = 0; j < 8; ++j) { a += red1[tid + 64 * j]; a2 += red2[tid + 64 * j]; }
        float m = a * (1.0f / C_);
        smean[tid] = m;
        srstd[tid] = rsqrtf(a2 * (1.0f / C_) - m * m + 1e-5f);
    }
    __syncthreads();
    #pragma unroll
    for (int r = 0; r < 16; ++r) {
        int idx = tid + (r << 9);
        int n_l = idx >> 7, cp = idx & 127;
        int c0 = cp << 1;
        float mn = smean[n_l], rs = srstd[n_l];
        float v0 = (tile[c0][n_l] - mn) * rs * sg[c0] + sb[c0];
        float v1 = (tile[c0 + 1][n_l] - mn) * rs * sg[c0 + 1] + sb[c0 + 1];
        ushort2 o; o.x = f2bf(v0); o.y = f2bf(v1);
        *reinterpret_cast<ushort2*>(&xnb[((size_t)(b * NPIX + nt + n_l)) * C_ + c0]) = o;
    }
}

// ---------------- init: slots + raw stats + Wqg/qoff partials. grid (2,64) ----------------
__global__ __launch_bounds__(256) void initqt_kernel(
    const float* __restrict__ noise, const float* __restrict__ mu,
    const float* __restrict__ log_sigma,
    const float* __restrict__ WqgT, const float* __restrict__ wqg,
    float* __restrict__ slots,
    float* __restrict__ qtp, float* __restrict__ qoffP,
    float* __restrict__ msumS, float* __restrict__ m2sumS,
    float* __restrict__ usum, float* __restrict__ denom) {
    __shared__ float srow[256];
    __shared__ float pq[256];
    __shared__ float r8[8];
    const int t = threadIdx.x, dq = blockIdx.x, r = blockIdx.y;
    float v = mu[t] + expf(log_sigma[t]) * noise[r * C_ + t];
    srow[t] = v;
    if (dq == 0) {
        slots[r * C_ + t] = v;
        usum[r * C_ + t] = 0.f;
        if (t == 0) denom[r] = 0.f;
        float a = v, b2s = v * v, c = wqg[t] * v;
        #pragma unroll
        for (int m = 1; m <= 32; m <<= 1) {
            a += __shfl_xor(a, m); b2s += __shfl_xor(b2s, m); c += __shfl_xor(c, m);
        }
        if ((t & 63) == 0) {
            int w4 = t >> 6;
            r8[w4] = a; r8[4 + w4] = b2s;
            pq[w4] = c;                 // reuse pq scratch (pre-matvec)
        }
    }
    __syncthreads();
    if (dq == 0 && t == 0) {
        msumS[r]  = r8[0] + r8[1] + r8[2] + r8[3];
        m2sumS[r] = r8[4] + r8[5] + r8[6] + r8[7];
        qoffP[r]  = pq[0] + pq[1] + pq[2] + pq[3];
    }
    __syncthreads();
    // qt partial: full Wqg.srow for d-tile [dq*128, dq*128+128)
    const int dl = t & 127, cs = t >> 7;
    const int d = dq * 128 + dl;
    float acc = 0.f;
    #pragma unroll 4
    for (int c = cs * 128; c < cs * 128 + 128; ++c)
        acc = fmaf(WqgT[c * 256 + d], srow[c], acc);
    pq[cs * 128 + dl] = acc;
    __syncthreads();
    if (t < 128) qtp[r * C_ + dq * 128 + t] = pq[t] + pq[128 + t];
}

// ---------------- updA: nv slice + mlp-LN stats + W1g partials. grid (8,64) ----------------
__global__ __launch_bounds__(256) void updA_kernel(
    const float* __restrict__ slots, const float* __restrict__ usum,
    const float* __restrict__ denom,
    const float4* __restrict__ WuC4, const float* __restrict__ bu,
    const float* __restrict__ bv2, const float* __restrict__ W1gT,
    float* __restrict__ nvbuf, float* __restrict__ hpp,
    float* __restrict__ msumN, float* __restrict__ m2sumN,
    float* __restrict__ qtp, float* __restrict__ qoffP,
    float* __restrict__ msumS, float* __restrict__ m2sumS,
    float* __restrict__ ep) {
    __shared__ __align__(16) float comb[512];
    __shared__ float pq[256];
    __shared__ float nvs[32];
    __shared__ float sden, sscale;
    const int t = threadIdx.x, dq = blockIdx.x, r = blockIdx.y;
    if (t == 0) { float dv = denom[r]; sden = dv + EPS_; sscale = dv / (dv + EPS_); }
    comb[t] = slots[r * C_ + t];
    float uv = usum[r * C_ + t];
    // zero next-phase accumulators (consumed by attn already; updB accumulates)
    if (t < 32) qtp[r * C_ + dq * 32 + t] = 0.f;
    if (dq < 4 && t < 32) ep[r * 128 + dq * 32 + t] = 0.f;
    if (dq == 0 && t == 0) { msumS[r] = 0.f; m2sumS[r] = 0.f; qoffP[r] = 0.f; }
    __syncthreads();
    comb[256 + t] = uv / sden;
    __syncthreads();
    // nv slice: 8 ksplit x 32 d
    const int dloc = t & 31, ks = t >> 5;
    const int d = dq * 32 + dloc;
    {
        const float4* cb4 = (const float4*)comb;
        float4 a0 = {0,0,0,0}, a1 = {0,0,0,0};
        int c4b = ks << 4;
        #pragma unroll
        for (int i = 0; i < 16; i += 2) {
            fma4(a0, WuC4[(c4b + i) * 256 + d], cb4[c4b + i]);
            fma4(a1, WuC4[(c4b + i + 1) * 256 + d], cb4[c4b + i + 1]);
        }
        pq[ks * 32 + dloc] = hsum4(a0) + hsum4(a1);
    }
    __syncthreads();
    if (t < 32) {
        int dd = dq * 32 + t;
        float s = 0.f;
        #pragma unroll
        for (int i = 0; i < 8; ++i) s += pq[i * 32 + t];
        float nv = s + bu[dd] + comb[dd] + sscale * bv2[dd];
        nvs[t] = nv;
        nvbuf[r * C_ + dd] = nv;
        float a = nv, b = nv * nv;
        #pragma unroll
        for (int m = 1; m <= 16; m <<= 1) { a += __shfl_xor(a, m); b += __shfl_xor(b, m); }
        if (t == 0) { atomicAdd(&msumN[r], a); atomicAdd(&m2sumN[r], b); }
    }
    __syncthreads();
    // W1g partials: j = t and t+256 over this block's 32-c slice
    {
        float a0 = 0.f, a1 = 0.f;
        const float* wb = W1gT + (size_t)(dq * 32) * 512;
        #pragma unroll 8
        for (int i = 0; i < 32; ++i) {
            float nv = nvs[i];
            a0 = fmaf(wb[i * 512 + t], nv, a0);
            a1 = fmaf(wb[i * 512 + 256 + t], nv, a1);
        }
        atomicAdd(&hpp[r * HID_ + t], a0);
        atomicAdd(&hpp[r * HID_ + 256 + t], a1);
    }
}

// ---------------- updB: finish h, W2 slice -> ov, qt/We1 partials. grid (8,64) ----------------
__global__ __launch_bounds__(256) void updB_kernel(
    const float* __restrict__ nvbuf, const float* __restrict__ hpp,
    const float* __restrict__ msumN, const float* __restrict__ m2sumN,
    const float* __restrict__ w1gsum, const float* __restrict__ w1bsum,
    const float4* __restrict__ W24, const float* __restrict__ b2,
    const float* __restrict__ WqgT, const float* __restrict__ wqg,
    const float* __restrict__ We1T,
    float* __restrict__ dst,
    float* __restrict__ qtp, float* __restrict__ qoffP,
    float* __restrict__ msumS, float* __restrict__ m2sumS,
    float* __restrict__ ep,
    float* __restrict__ usum, float* __restrict__ denom, int fin) {
    __shared__ __align__(16) float hrow[512];
    __shared__ float pq[256];
    __shared__ float ovs[32];
    const int t = threadIdx.x, dq = blockIdx.x, r = blockIdx.y;
    float mN = msumN[r] * (1.f / C_);
    float rsN = rsqrtf(m2sumN[r] * (1.f / C_) - mN * mN + 1e-5f);
    hrow[t]       = gelu_f(rsN * (hpp[r * HID_ + t]       - mN * w1gsum[t])       + w1bsum[t]);
    hrow[256 + t] = gelu_f(rsN * (hpp[r * HID_ + 256 + t] - mN * w1gsum[256 + t]) + w1bsum[256 + t]);
    // zero usum/denom for next attn
    if (t < 32) usum[r * C_ + dq * 32 + t] = 0.f;
    if (dq == 0 && t == 0) denom[r] = 0.f;
    __syncthreads();
    // W2 slice: 8 ksplit x 32 d
    const int dloc = t & 31, ks = t >> 5;
    const int d = dq * 32 + dloc;
    {
        const float4* h4 = (const float4*)hrow;
        float4 a0 = {0,0,0,0}, a1 = {0,0,0,0};
        int h4b = ks << 4;
        #pragma unroll
        for (int i = 0; i < 16; i += 2) {
            fma4(a0, W24[(h4b + i) * 256 + d], h4[h4b + i]);
            fma4(a1, W24[(h4b + i + 1) * 256 + d], h4[h4b + i + 1]);
        }
        pq[ks * 32 + dloc] = hsum4(a0) + hsum4(a1);
    }
    __syncthreads();
    if (t < 32) {
        int dd = dq * 32 + t;
        float s = 0.f;
        #pragma unroll
        for (int i = 0; i < 8; ++i) s += pq[i * 32 + t];
        float ov = nvbuf[r * C_ + dd] + s + b2[dd];
        ovs[t] = ov;
        dst[r * C_ + dd] = ov;
        float a = ov, b = ov * ov;
        #pragma unroll
        for (int m = 1; m <= 16; m <<= 1) { a += __shfl_xor(a, m); b += __shfl_xor(b, m); }
        if (t == 0) { atomicAdd(&msumS[r], a); atomicAdd(&m2sumS[r], b); }
    }
    __syncthreads();
    if (!fin) {
        // qt partials: d = t over this block's 32-c slice
        float acc = 0.f;
        const float* wb = WqgT + (size_t)(dq * 32) * 256;
        #pragma unroll 8
        for (int i = 0; i < 32; ++i)
            acc = fmaf(wb[i * 256 + t], ovs[i], acc);
        atomicAdd(&qtp[r * C_ + t], acc);
        if (t < 32) {
            float p = wqg[dq * 32 + t] * ovs[t];
            #pragma unroll
            for (int m = 1; m <= 16; m <<= 1) p += __shfl_xor(p, m);
            if (t == 0) atomicAdd(&qoffP[r], p);
        }
    } else {
        // We1 partials: e = t&127, two c-halves
        const int e = t & 127, half = t >> 7;
        float acc = 0.f;
        const float* wb = We1T + (size_t)(dq * 32 + half * 16) * 128;
        #pragma unroll
        for (int i = 0; i < 16; ++i)
            acc = fmaf(wb[i * 128 + e], ovs[half * 16 + i], acc);
        atomicAdd(&ep[r * 128 + e], acc);
    }
}

// ---------------- head finish: grid 64, 128 threads ----------------
__global__ __launch_bounds__(128) void head_fin_kernel(
    const float* __restrict__ ep, const float* __restrict__ be1,
    const float* __restrict__ We2, const float* __restrict__ be2,
    float* __restrict__ out) {
    __shared__ float r2[2];
    const int t = threadIdx.x, r = blockIdx.x;
    float ev = gelu_f(ep[r * 128 + t] + be1[t]);
    float p = We2[t] * ev;
    #pragma unroll
    for (int m = 1; m <= 32; m <<= 1) p += __shfl_xor(p, m);
    if ((t & 63) == 0) r2[t >> 6] = p;
    __syncthreads();
    if (t == 0) out[B_ * K_ * C_ + r] = 1.0f / (1.0f + expf(-(r2[0] + r2[1] + be2[0])));
}

// ---------------- fused attention (64-pixel chunks) + qt affine finish ----------------
__global__ __launch_bounds__(256) void attn_fused_kernel(
    const float* __restrict__ qtp, const float* __restrict__ qoffP,
    const float* __restrict__ msumS, const float* __restrict__ m2sumS,
    const float* __restrict__ wqgsum, const float* __restrict__ wqbsum,
    const float* __restrict__ wqS,
    const unsigned short* __restrict__ xnb,
    float* __restrict__ usum, float* __restrict__ denom,
    float* __restrict__ hpp, float* __restrict__ msumN, float* __restrict__ m2sumN) {
    __shared__ float4 qT[264];
    __shared__ float attns[K_][64];
    __shared__ float upd_s[K_][256];
    __shared__ float asw[4][4];
    __shared__ float4 qo_s;
    __shared__ float s_m[4], s_rs[4];

    const int tid = threadIdx.x;
    const int b = blockIdx.y;
    const int chunk = blockIdx.x;
    const int n0 = chunk << 6;
    const int wave = tid >> 6, lane = tid & 63;

    if (tid < 4) {
        float ms = msumS[b * 4 + tid] * (1.f / C_);
        float m2 = m2sumS[b * 4 + tid] * (1.f / C_);
        s_m[tid] = ms;
        s_rs[tid] = rsqrtf(m2 - ms * ms + 1e-5f);
    }
    // housekeeping zero (for this iteration's updA accumulation)
    if (chunk < 8) hpp[(size_t)(b * 4 + (chunk >> 1)) * HID_ + (chunk & 1) * 256 + tid] = 0.f;
    else if (chunk == 8) {
        if (tid < 4) msumN[b * 4 + tid] = 0.f;
        else if (tid < 8) m2sumN[b * 4 + tid - 4] = 0.f;
    }
    __syncthreads();
    {
        int c = tid;
        float wg = wqgsum[c], wb = wqbsum[c];
        float4 qv;
        qv.x = s_rs[0] * (qtp[(b * 4 + 0) * C_ + c] - s_m[0] * wg) + wb;
        qv.y = s_rs[1] * (qtp[(b * 4 + 1) * C_ + c] - s_m[1] * wg) + wb;
        qv.z = s_rs[2] * (qtp[(b * 4 + 2) * C_ + c] - s_m[2] * wg) + wb;
        qv.w = s_rs[3] * (qtp[(b * 4 + 3) * C_ + c] - s_m[3] * wg) + wb;
        qT[c + (c >> 5)] = qv;
        if (tid == 0) {
            float S1 = wqS[0], S2 = wqS[1];
            float4 qo;
            qo.x = s_rs[0] * (qoffP[b * 4 + 0] - s_m[0] * S1) + S2;
            qo.y = s_rs[1] * (qoffP[b * 4 + 1] - s_m[1] * S1) + S2;
            qo.z = s_rs[2] * (qoffP[b * 4 + 2] - s_m[2] * S1) + S2;
            qo.w = s_rs[3] * (qoffP[b * 4 + 3] - s_m[3] * S1) + S2;
            qo_s = qo;
        }
    }
    __syncthreads();

    const int cpart = tid & 7;
    const int npair = tid >> 3;
    const int c0 = cpart << 5;
    float4 acc0 = {0.f, 0.f, 0.f, 0.f}, acc1 = {0.f, 0.f, 0.f, 0.f};
    const unsigned short* kbase = xnb + ((size_t)b * NPIX + n0 + npair * 2) * C_ + c0;
    #pragma unroll
    for (int j = 0; j < 4; ++j) {
        uint4 k0 = *reinterpret_cast<const uint4*>(kbase + j * 8);
        uint4 k1 = *reinterpret_cast<const uint4*>(kbase + C_ + j * 8);
        const unsigned kw0[4] = {k0.x, k0.y, k0.z, k0.w};
        const unsigned kw1[4] = {k1.x, k1.y, k1.z, k1.w};
        #pragma unroll
        for (int jj = 0; jj < 4; ++jj) {
            int cidx = c0 + j * 8 + jj * 2 + cpart;
            float4 qa = qT[cidx];
            float4 qb = qT[cidx + 1];
            float f00 = bflo(kw0[jj]), f01 = bfhi(kw0[jj]);
            float f10 = bflo(kw1[jj]), f11 = bfhi(kw1[jj]);
            acc0.x += f00 * qa.x + f01 * qb.x;  acc0.y += f00 * qa.y + f01 * qb.y;
            acc0.z += f00 * qa.z + f01 * qb.z;  acc0.w += f00 * qa.w + f01 * qb.w;
            acc1.x += f10 * qa.x + f11 * qb.x;  acc1.y += f10 * qa.y + f11 * qb.y;
            acc1.z += f10 * qa.z + f11 * qb.z;  acc1.w += f10 * qa.w + f11 * qb.w;
        }
    }
    #pragma unroll
    for (int m = 1; m <= 4; m <<= 1) {
        acc0 = acc0 + shfl_xor4(acc0, m);
        acc1 = acc1 + shfl_xor4(acc1, m);
    }
    float4 w0, w1;
    {
        float4 l = (acc0 + qo_s) * 0.0625f;
        float mx = fmaxf(fmaxf(l.x, l.y), fmaxf(l.z, l.w));
        w0.x = expf(l.x - mx); w0.y = expf(l.y - mx);
        w0.z = expf(l.z - mx); w0.w = expf(l.w - mx);
        float inv = 1.0f / (w0.x + w0.y + w0.z + w0.w);
        w0 = w0 * inv;
        l = (acc1 + qo_s) * 0.0625f;
        mx = fmaxf(fmaxf(l.x, l.y), fmaxf(l.z, l.w));
        w1.x = expf(l.x - mx); w1.y = expf(l.y - mx);
        w1.z = expf(l.z - mx); w1.w = expf(l.w - mx);
        inv = 1.0f / (w1.x + w1.y + w1.z + w1.w);
        w1 = w1 * inv;
    }
    if (cpart == 0) {
        int n_l = npair * 2;
        attns[0][n_l] = w0.x; attns[1][n_l] = w0.y; attns[2][n_l] = w0.z; attns[3][n_l] = w0.w;
        attns[0][n_l + 1] = w1.x; attns[1][n_l + 1] = w1.y;
        attns[2][n_l + 1] = w1.z; attns[3][n_l + 1] = w1.w;
    }
    float4 ws = w0 + w1;
    #pragma unroll
    for (int m = 8; m <= 32; m <<= 1) ws = ws + shfl_xor4(ws, m);
    if (lane == 0) {
        asw[wave][0] = ws.x; asw[wave][1] = ws.y; asw[wave][2] = ws.z; asw[wave][3] = ws.w;
    }
    __syncthreads();
    if (tid < 4)
        atomicAdd(&denom[b * 4 + tid],
                  asw[0][tid] + asw[1][tid] + asw[2][tid] + asw[3][tid]);

    const int h = wave >> 1;
    const int chalf = (wave & 1) << 7;
    const int c = chalf + lane * 2;
    float a0[K_] = {0.f, 0.f, 0.f, 0.f};
    float a1[K_] = {0.f, 0.f, 0.f, 0.f};
    const unsigned short* vbase = xnb + ((size_t)b * NPIX + n0 + h * 32) * C_ + c;
    #pragma unroll 4
    for (int nn = 0; nn < 32; ++nn) {
        unsigned vv = *reinterpret_cast<const unsigned*>(vbase + (size_t)nn * C_);
        float v0 = bflo(vv), v1 = bfhi(vv);
        int n_l = h * 32 + nn;
        float q0 = attns[0][n_l], q1 = attns[1][n_l], q2 = attns[2][n_l], q3 = attns[3][n_l];
        a0[0] = fmaf(q0, v0, a0[0]); a1[0] = fmaf(q0, v1, a1[0]);
        a0[1] = fmaf(q1, v0, a0[1]); a1[1] = fmaf(q1, v1, a1[1]);
        a0[2] = fmaf(q2, v0, a0[2]); a1[2] = fmaf(q2, v1, a1[2]);
        a0[3] = fmaf(q3, v0, a0[3]); a1[3] = fmaf(q3, v1, a1[3]);
    }
    __syncthreads();
    if (h == 0) {
        #pragma unroll
        for (int k = 0; k < K_; ++k) { upd_s[k][c] = a0[k]; upd_s[k][c + 1] = a1[k]; }
    }
    __syncthreads();
    if (h == 1) {
        #pragma unroll
        for (int k = 0; k < K_; ++k) { upd_s[k][c] += a0[k]; upd_s[k][c + 1] += a1[k]; }
    }
    __syncthreads();
    #pragma unroll
    for (int k = 0; k < K_; ++k)
        atomicAdd(&usum[((size_t)b * K_ + k) * 256 + tid], upd_s[k][tid]);
}

extern "C" void kernel_launch(void* const* d_in, const int* in_sizes, int n_in,
                              void* d_out, int out_size, void* d_ws, size_t ws_size,
                              hipStream_t stream) {
    (void)in_sizes; (void)n_in; (void)out_size; (void)ws_size;
    const float* x        = (const float*)d_in[0];
    const float* noise    = (const float*)d_in[1];
    const float* slot_mu  = (const float*)d_in[2];
    const float* slot_ls  = (const float*)d_in[3];
    const float* ln_in_g  = (const float*)d_in[4];
    const float* ln_in_b  = (const float*)d_in[5];
    const float* ln_sl_g  = (const float*)d_in[6];
    const float* ln_sl_b  = (const float*)d_in[7];
    const float* ln_mlp_g = (const float*)d_in[8];
    const float* ln_mlp_b = (const float*)d_in[9];
    const float* Wq = (const float*)d_in[10];
    const float* bq = (const float*)d_in[11];
    const float* Wk = (const float*)d_in[12];
    const float* bk = (const float*)d_in[13];
    const float* Wv = (const float*)d_in[14];
    const float* bv = (const float*)d_in[15];
    const float* Wu = (const float*)d_in[16];
    const float* bu = (const float*)d_in[17];
    const float* W1 = (const float*)d_in[18];
    const float* b1 = (const float*)d_in[19];
    const float* W2 = (const float*)d_in[20];
    const float* b2 = (const float*)d_in[21];
    const float* We1 = (const float*)d_in[22];
    const float* be1 = (const float*)d_in[23];
    const float* We2 = (const float*)d_in[24];
    const float* be2 = (const float*)d_in[25];
    float* out = (float*)d_out;

    char* ws = (char*)d_ws;
    unsigned short* xnb = (unsigned short*)ws;                  // 32 MiB
    float4* WuC4  = (float4*)(xnb + (size_t)NROWS * C_);        // 32768 f4
    float4* W24   = WuC4 + 32768;                               // 32768 f4
    float* W1gT   = (float*)(W24 + 32768);                      // 131072
    float* WqgT   = W1gT + 131072;                              // 65536
    float* We1T   = WqgT + 65536;                               // 32768
    float* w1gsum = We1T + 32768;                               // 512
    float* w1bsum = w1gsum + 512;                               // 512
    float* wqgsum = w1bsum + 512;                               // 256
    float* wqbsum = wqgsum + 256;                               // 256
    float* wqg    = wqbsum + 256;                               // 256
    float* wqS    = wqg + 256;                                  // 2 (+pad)
    float* bv2    = wqS + 4;                                    // 256
    float* slots  = bv2 + 256;                                  // 16384
    float* nvbuf  = slots + B_ * K_ * C_;                       // 16384
    float* qtp    = nvbuf + B_ * K_ * C_;                       // 16384
    float* qoffP  = qtp + B_ * K_ * C_;                         // 64
    float* msumS  = qoffP + B_ * K_;                            // 64
    float* m2sumS = msumS + B_ * K_;                            // 64
    float* hpp    = m2sumS + B_ * K_;                           // 32768
    float* msumN  = hpp + B_ * K_ * HID_;                       // 64
    float* m2sumN = msumN + B_ * K_;                            // 64
    float* usum   = m2sumN + B_ * K_;                           // 16384
    float* denom  = usum + B_ * K_ * C_;                        // 64
    float* ep     = denom + B_ * K_;                            // 8192

    prep_all_kernel<<<1091, 256, 0, stream>>>(
        Wu, W1, W2, We1, Wq, Wk, Wv, bk, bq, bv, b1,
        ln_sl_g, ln_sl_b, ln_mlp_g, ln_mlp_b,
        WuC4, W24, W1gT, WqgT, We1T,
        w1gsum, w1bsum, wqgsum, wqbsum, wqg, wqS, bv2);
    xn_fused_kernel<<<dim3(64, 16), 512, 0, stream>>>(x, ln_in_g, ln_in_b, xnb);
    initqt_kernel<<<dim3(2, B_ * K_), 256, 0, stream>>>(
        noise, slot_mu, slot_ls, WqgT, wqg,
        slots, qtp, qoffP, msumS, m2sumS, usum, denom);
    for (int it = 0; it < ITERS_; ++it) {
        const int fin = (it == ITERS_ - 1);
        attn_fused_kernel<<<dim3(64, 16), 256, 0, stream>>>(
            qtp, qoffP, msumS, m2sumS, wqgsum, wqbsum, wqS,
            xnb, usum, denom, hpp, msumN, m2sumN);
        updA_kernel<<<dim3(8, B_ * K_), 256, 0, stream>>>(
            slots, usum, denom, WuC4, bu, bv2, W1gT,
            nvbuf, hpp, msumN, m2sumN, qtp, qoffP, msumS, m2sumS, ep);
        updB_kernel<<<dim3(8, B_ * K_), 256, 0, stream>>>(
            nvbuf, hpp, msumN, m2sumN, w1gsum, w1bsum, W24, b2,
            WqgT, wqg, We1T, fin ? out : slots,
            qtp, qoffP, msumS, m2sumS, ep, usum, denom, fin);
    }
    head_fin_kernel<<<B_ * K_, 128, 0, stream>>>(ep, be1, We2, be2, out);
}

// Round 8
// 300.592 us; speedup vs baseline: 1.2060x; 1.0032x over previous
//
#include <hip/hip_runtime.h>
#include <math.h>

#define B_    16
#define C_    256
#define NPIX  4096      // H*W
#define K_    4
#define HID_  512
#define ITERS_ 3
#define NROWS (B_*NPIX) // 65536
#define EPS_  1e-8f

__device__ __forceinline__ float gelu_f(float x) {
    return 0.5f * x * (1.0f + erff(x * 0.70710678118654752f));
}

__device__ __forceinline__ unsigned short f2bf(float x) {
    union { float f; unsigned u; } v; v.f = x;
    unsigned r = v.u + 0x7fffu + ((v.u >> 16) & 1u);   // round-nearest-even
    return (unsigned short)(r >> 16);
}
__device__ __forceinline__ float bflo(unsigned u) {
    union { unsigned u; float f; } v; v.u = u << 16; return v.f;
}
__device__ __forceinline__ float bfhi(unsigned u) {
    union { unsigned u; float f; } v; v.u = u & 0xffff0000u; return v.f;
}
__device__ __forceinline__ float4 shfl_xor4(float4 v, int m) {
    v.x = __shfl_xor(v.x, m); v.y = __shfl_xor(v.y, m);
    v.z = __shfl_xor(v.z, m); v.w = __shfl_xor(v.w, m);
    return v;
}
__device__ __forceinline__ void fma4(float4& a, const float4 w, const float4 s) {
    a.x = fmaf(w.x, s.x, a.x); a.y = fmaf(w.y, s.y, a.y);
    a.z = fmaf(w.z, s.z, a.z); a.w = fmaf(w.w, s.w, a.w);
}
__device__ __forceinline__ float hsum4(const float4 a) {
    return (a.x + a.y) + (a.z + a.w);
}

// ---------------- prep: packed + composed + LN-folded weights (r6, proven) ----------------
__global__ __launch_bounds__(256) void prep_all_kernel(
    const float* __restrict__ Wu, const float* __restrict__ W1,
    const float* __restrict__ W2, const float* __restrict__ We1,
    const float* __restrict__ Wq, const float* __restrict__ Wk,
    const float* __restrict__ Wv,
    const float* __restrict__ bk, const float* __restrict__ bq,
    const float* __restrict__ bv, const float* __restrict__ b1,
    const float* __restrict__ g_sl, const float* __restrict__ b_sl,
    const float* __restrict__ g_mlp, const float* __restrict__ b_mlp,
    float4* __restrict__ WuC4, float4* __restrict__ W24,
    float* __restrict__ W1gT, float* __restrict__ WqgT,
    float* __restrict__ We1T,
    float* __restrict__ w1gsum, float* __restrict__ w1bsum,
    float* __restrict__ wqgsum, float* __restrict__ wqbsum,
    float* __restrict__ wqg, float* __restrict__ wqS,
    float* __restrict__ bv2) {
    const int role = blockIdx.x;
    const int t = threadIdx.x;
    if (role < 64) {
        int i = role * 256 + t;
        int c4 = i >> 8, dd = i & 255;
        WuC4[i] = *(const float4*)&Wu[dd * 512 + c4 * 4];
        return;
    }
    if (role < 192) {
        int j = (role - 64) * 256 + t;
        int h4 = j >> 8, dd = j & 255;
        W24[j] = *(const float4*)&W2[dd * 512 + h4 * 4];
        return;
    }
    if (role < 704) {
        int idx = (role - 192) * 256 + t;
        int c = idx & 255, jj = idx >> 8;
        W1gT[c * 512 + jj] = W1[jj * 256 + c] * g_mlp[c];
        return;
    }
    if (role < 832) {
        int idx = (role - 704) * 256 + t;
        int c = idx & 255, e = idx >> 8;
        We1T[c * 128 + e] = We1[e * 256 + c];
        return;
    }
    if (role == 832) {
        __shared__ float r12[12];
        int c = t;
        float w = 0.f;
        for (int dd = 0; dd < 256; ++dd) w = fmaf(Wq[dd * 256 + c], bk[dd], w);
        wqg[c] = w * g_sl[c];
        float pA = w * g_sl[c], pB = w * b_sl[c], pC = bq[c] * bk[c];
        #pragma unroll
        for (int m = 1; m <= 32; m <<= 1) {
            pA += __shfl_xor(pA, m); pB += __shfl_xor(pB, m); pC += __shfl_xor(pC, m);
        }
        if ((c & 63) == 0) {
            int w4 = c >> 6;
            r12[w4] = pA; r12[4 + w4] = pB; r12[8 + w4] = pC;
        }
        __syncthreads();
        if (c == 0) {
            wqS[0] = r12[0] + r12[1] + r12[2] + r12[3];
            wqS[1] = (r12[4] + r12[5] + r12[6] + r12[7])
                   + (r12[8] + r12[9] + r12[10] + r12[11]);
        }
        return;
    }
    if (role < 835) {
        int j = (role - 833) * 256 + t;
        float sg = 0.f, sb = 0.f;
        for (int c = 0; c < 256; ++c) {
            float w = W1[j * 256 + c];
            sg = fmaf(w, g_mlp[c], sg);
            sb = fmaf(w, b_mlp[c], sb);
        }
        w1gsum[j] = sg;
        w1bsum[j] = sb + b1[j];
        return;
    }
    {
        __shared__ float wur[256], wkc[256];
        __shared__ float ldsA[256];
        __shared__ float r16[16];
        const int d = role - 835, c = t;
        wur[c] = Wu[d * 512 + 256 + c];
        wkc[c] = Wk[c * 256 + d];
        __syncthreads();
        float a = 0.f, b = 0.f;
        #pragma unroll 4
        for (int e = 0; e < 256; ++e) {
            a = fmaf(wur[e], Wv[e * 256 + c], a);
            b = fmaf(wkc[e], Wq[e * 256 + c], b);
        }
        ldsA[c] = a;
        WqgT[c * 256 + d] = b * g_sl[c];
        float pA = wur[c] * bv[c];
        float pB = wkc[c] * bq[c];
        float pC = b * g_sl[c];
        float pD = b * b_sl[c];
        #pragma unroll
        for (int m = 1; m <= 32; m <<= 1) {
            pA += __shfl_xor(pA, m); pB += __shfl_xor(pB, m);
            pC += __shfl_xor(pC, m); pD += __shfl_xor(pD, m);
        }
        if ((c & 63) == 0) {
            int w4 = c >> 6;
            r16[w4] = pA; r16[4 + w4] = pB; r16[8 + w4] = pC; r16[12 + w4] = pD;
        }
        __syncthreads();
        if (c < 64) {
            float4 qa = { ldsA[4 * c], ldsA[4 * c + 1], ldsA[4 * c + 2], ldsA[4 * c + 3] };
            WuC4[(64 + c) * 256 + d] = qa;
        }
        if (c == 0) {
            bv2[d] = r16[0] + r16[1] + r16[2] + r16[3];
            float bqk = r16[4] + r16[5] + r16[6] + r16[7];
            wqgsum[d] = r16[8] + r16[9] + r16[10] + r16[11];
            wqbsum[d] = (r16[12] + r16[13] + r16[14] + r16[15]) + bqk;
        }
    }
}

// ---------------- xn: 32-px tiles, 512 threads, register stats, 4 blocks/CU ----------------
__global__ __launch_bounds__(512) void xn_fused_kernel(
    const float* __restrict__ x, const float* __restrict__ g, const float* __restrict__ bta,
    unsigned short* __restrict__ xnb) {
    __shared__ float tile[256][33];
    __shared__ float wsum[8][32], wsum2[8][32];
    __shared__ float smean[32], srstd[32];
    const int tid = threadIdx.x;
    const int nt = blockIdx.x << 5, b = blockIdx.y;

    float s = 0.f, s2 = 0.f;
    #pragma unroll
    for (int r = 0; r < 16; ++r) {
        int idx = tid + (r << 9);
        int c_l = idx >> 5, n_l = idx & 31;
        float v = x[(size_t)(b * C_ + c_l) * NPIX + nt + n_l];
        tile[c_l][n_l] = v;
        s += v; s2 += v * v;
    }
    s += __shfl_xor(s, 32); s2 += __shfl_xor(s2, 32);
    {
        int lane = tid & 63, w = tid >> 6;
        if (lane < 32) { wsum[w][lane] = s; wsum2[w][lane] = s2; }
    }
    __syncthreads();
    if (tid < 32) {
        float a = 0.f, a2 = 0.f;
        #pragma unroll
        for (int j = 0; j < 8; ++j) { a += wsum[j][tid]; a2 += wsum2[j][tid]; }
        float m = a * (1.0f / C_);
        smean[tid] = m;
        srstd[tid] = rsqrtf(a2 * (1.0f / C_) - m * m + 1e-5f);
    }
    __syncthreads();
    #pragma unroll
    for (int r = 0; r < 8; ++r) {
        int idx = tid + (r << 9);
        int n_l = idx >> 7, cp = idx & 127;
        int c0 = cp << 1;
        float mn = smean[n_l], rs = srstd[n_l];
        float v0 = (tile[c0][n_l] - mn) * rs * g[c0] + bta[c0];
        float v1 = (tile[c0 + 1][n_l] - mn) * rs * g[c0 + 1] + bta[c0 + 1];
        ushort2 o; o.x = f2bf(v0); o.y = f2bf(v1);
        *reinterpret_cast<ushort2*>(&xnb[((size_t)(b * NPIX + nt + n_l)) * C_ + c0]) = o;
    }
}

// ---------------- init: slots + raw stats + Wqg/qoff partials (r6, proven) ----------------
__global__ __launch_bounds__(256) void initqt_kernel(
    const float* __restrict__ noise, const float* __restrict__ mu,
    const float* __restrict__ log_sigma,
    const float* __restrict__ WqgT, const float* __restrict__ wqg,
    float* __restrict__ slots,
    float* __restrict__ qtp, float* __restrict__ qoffP,
    float* __restrict__ msumS, float* __restrict__ m2sumS,
    float* __restrict__ usum, float* __restrict__ denom) {
    __shared__ float srow[256];
    __shared__ float pq[256];
    __shared__ float r8[8];
    const int t = threadIdx.x, dq = blockIdx.x, r = blockIdx.y;
    float v = mu[t] + expf(log_sigma[t]) * noise[r * C_ + t];
    srow[t] = v;
    if (dq == 0) {
        slots[r * C_ + t] = v;
        usum[r * C_ + t] = 0.f;
        if (t == 0) denom[r] = 0.f;
        float a = v, b2s = v * v, c = wqg[t] * v;
        #pragma unroll
        for (int m = 1; m <= 32; m <<= 1) {
            a += __shfl_xor(a, m); b2s += __shfl_xor(b2s, m); c += __shfl_xor(c, m);
        }
        if ((t & 63) == 0) {
            int w4 = t >> 6;
            r8[w4] = a; r8[4 + w4] = b2s;
            pq[w4] = c;
        }
    }
    __syncthreads();
    if (dq == 0 && t == 0) {
        msumS[r]  = r8[0] + r8[1] + r8[2] + r8[3];
        m2sumS[r] = r8[4] + r8[5] + r8[6] + r8[7];
        qoffP[r]  = pq[0] + pq[1] + pq[2] + pq[3];
    }
    __syncthreads();
    const int dl = t & 127, cs = t >> 7;
    const int d = dq * 128 + dl;
    float acc = 0.f;
    #pragma unroll 4
    for (int c = cs * 128; c < cs * 128 + 128; ++c)
        acc = fmaf(WqgT[c * 256 + d], srow[c], acc);
    pq[cs * 128 + dl] = acc;
    __syncthreads();
    if (t < 128) qtp[r * C_ + dq * 128 + t] = pq[t] + pq[128 + t];
}

// ---------------- updA: nv slice + mlp-LN stats + W1g partials (r6, proven) ----------------
__global__ __launch_bounds__(256) void updA_kernel(
    const float* __restrict__ slots, const float* __restrict__ usum,
    const float* __restrict__ denom,
    const float4* __restrict__ WuC4, const float* __restrict__ bu,
    const float* __restrict__ bv2, const float* __restrict__ W1gT,
    float* __restrict__ nvbuf, float* __restrict__ hpp,
    float* __restrict__ msumN, float* __restrict__ m2sumN,
    float* __restrict__ qtp, float* __restrict__ qoffP,
    float* __restrict__ msumS, float* __restrict__ m2sumS,
    float* __restrict__ ep) {
    __shared__ __align__(16) float comb[512];
    __shared__ float pq[256];
    __shared__ float nvs[32];
    __shared__ float sden, sscale;
    const int t = threadIdx.x, dq = blockIdx.x, r = blockIdx.y;
    if (t == 0) { float dv = denom[r]; sden = dv + EPS_; sscale = dv / (dv + EPS_); }
    comb[t] = slots[r * C_ + t];
    float uv = usum[r * C_ + t];
    if (t < 32) qtp[r * C_ + dq * 32 + t] = 0.f;
    if (dq < 4 && t < 32) ep[r * 128 + dq * 32 + t] = 0.f;
    if (dq == 0 && t == 0) { msumS[r] = 0.f; m2sumS[r] = 0.f; qoffP[r] = 0.f; }
    __syncthreads();
    comb[256 + t] = uv / sden;
    __syncthreads();
    const int dloc = t & 31, ks = t >> 5;
    const int d = dq * 32 + dloc;
    {
        const float4* cb4 = (const float4*)comb;
        float4 a0 = {0,0,0,0}, a1 = {0,0,0,0};
        int c4b = ks << 4;
        #pragma unroll
        for (int i = 0; i < 16; i += 2) {
            fma4(a0, WuC4[(c4b + i) * 256 + d], cb4[c4b + i]);
            fma4(a1, WuC4[(c4b + i + 1) * 256 + d], cb4[c4b + i + 1]);
        }
        pq[ks * 32 + dloc] = hsum4(a0) + hsum4(a1);
    }
    __syncthreads();
    if (t < 32) {
        int dd = dq * 32 + t;
        float s = 0.f;
        #pragma unroll
        for (int i = 0; i < 8; ++i) s += pq[i * 32 + t];
        float nv = s + bu[dd] + comb[dd] + sscale * bv2[dd];
        nvs[t] = nv;
        nvbuf[r * C_ + dd] = nv;
        float a = nv, b = nv * nv;
        #pragma unroll
        for (int m = 1; m <= 16; m <<= 1) { a += __shfl_xor(a, m); b += __shfl_xor(b, m); }
        if (t == 0) { atomicAdd(&msumN[r], a); atomicAdd(&m2sumN[r], b); }
    }
    __syncthreads();
    {
        float a0 = 0.f, a1 = 0.f;
        const float* wb = W1gT + (size_t)(dq * 32) * 512;
        #pragma unroll 8
        for (int i = 0; i < 32; ++i) {
            float nv = nvs[i];
            a0 = fmaf(wb[i * 512 + t], nv, a0);
            a1 = fmaf(wb[i * 512 + 256 + t], nv, a1);
        }
        atomicAdd(&hpp[r * HID_ + t], a0);
        atomicAdd(&hpp[r * HID_ + 256 + t], a1);
    }
}

// ---------------- updB: finish h, W2 slice -> ov, qt/We1 partials (r6, proven) -------------
__global__ __launch_bounds__(256) void updB_kernel(
    const float* __restrict__ nvbuf, const float* __restrict__ hpp,
    const float* __restrict__ msumN, const float* __restrict__ m2sumN,
    const float* __restrict__ w1gsum, const float* __restrict__ w1bsum,
    const float4* __restrict__ W24, const float* __restrict__ b2,
    const float* __restrict__ WqgT, const float* __restrict__ wqg,
    const float* __restrict__ We1T,
    float* __restrict__ dst,
    float* __restrict__ qtp, float* __restrict__ qoffP,
    float* __restrict__ msumS, float* __restrict__ m2sumS,
    float* __restrict__ ep,
    float* __restrict__ usum, float* __restrict__ denom, int fin) {
    __shared__ __align__(16) float hrow[512];
    __shared__ float pq[256];
    __shared__ float ovs[32];
    const int t = threadIdx.x, dq = blockIdx.x, r = blockIdx.y;
    float mN = msumN[r] * (1.f / C_);
    float rsN = rsqrtf(m2sumN[r] * (1.f / C_) - mN * mN + 1e-5f);
    hrow[t]       = gelu_f(rsN * (hpp[r * HID_ + t]       - mN * w1gsum[t])       + w1bsum[t]);
    hrow[256 + t] = gelu_f(rsN * (hpp[r * HID_ + 256 + t] - mN * w1gsum[256 + t]) + w1bsum[256 + t]);
    if (t < 32) usum[r * C_ + dq * 32 + t] = 0.f;
    if (dq == 0 && t == 0) denom[r] = 0.f;
    __syncthreads();
    const int dloc = t & 31, ks = t >> 5;
    const int d = dq * 32 + dloc;
    {
        const float4* h4 = (const float4*)hrow;
        float4 a0 = {0,0,0,0}, a1 = {0,0,0,0};
        int h4b = ks << 4;
        #pragma unroll
        for (int i = 0; i < 16; i += 2) {
            fma4(a0, W24[(h4b + i) * 256 + d], h4[h4b + i]);
            fma4(a1, W24[(h4b + i + 1) * 256 + d], h4[h4b + i + 1]);
        }
        pq[ks * 32 + dloc] = hsum4(a0) + hsum4(a1);
    }
    __syncthreads();
    if (t < 32) {
        int dd = dq * 32 + t;
        float s = 0.f;
        #pragma unroll
        for (int i = 0; i < 8; ++i) s += pq[i * 32 + t];
        float ov = nvbuf[r * C_ + dd] + s + b2[dd];
        ovs[t] = ov;
        dst[r * C_ + dd] = ov;
        float a = ov, b = ov * ov;
        #pragma unroll
        for (int m = 1; m <= 16; m <<= 1) { a += __shfl_xor(a, m); b += __shfl_xor(b, m); }
        if (t == 0) { atomicAdd(&msumS[r], a); atomicAdd(&m2sumS[r], b); }
    }
    __syncthreads();
    if (!fin) {
        float acc = 0.f;
        const float* wb = WqgT + (size_t)(dq * 32) * 256;
        #pragma unroll 8
        for (int i = 0; i < 32; ++i)
            acc = fmaf(wb[i * 256 + t], ovs[i], acc);
        atomicAdd(&qtp[r * C_ + t], acc);
        if (t < 32) {
            float p = wqg[dq * 32 + t] * ovs[t];
            #pragma unroll
            for (int m = 1; m <= 16; m <<= 1) p += __shfl_xor(p, m);
            if (t == 0) atomicAdd(&qoffP[r], p);
        }
    } else {
        const int e = t & 127, half = t >> 7;
        float acc = 0.f;
        const float* wb = We1T + (size_t)(dq * 32 + half * 16) * 128;
        #pragma unroll
        for (int i = 0; i < 16; ++i)
            acc = fmaf(wb[i * 128 + e], ovs[half * 16 + i], acc);
        atomicAdd(&ep[r * 128 + e], acc);
    }
}

// ---------------- head finish (r6, proven) ----------------
__global__ __launch_bounds__(128) void head_fin_kernel(
    const float* __restrict__ ep, const float* __restrict__ be1,
    const float* __restrict__ We2, const float* __restrict__ be2,
    float* __restrict__ out) {
    __shared__ float r2[2];
    const int t = threadIdx.x, r = blockIdx.x;
    float ev = gelu_f(ep[r * 128 + t] + be1[t]);
    float p = We2[t] * ev;
    #pragma unroll
    for (int m = 1; m <= 32; m <<= 1) p += __shfl_xor(p, m);
    if ((t & 63) == 0) r2[t >> 6] = p;
    __syncthreads();
    if (t == 0) out[B_ * K_ * C_ + r] = 1.0f / (1.0f + expf(-(r2[0] + r2[1] + be2[0])));
}

// ---------------- fused attention: xnb read ONCE (LDS-staged tile) + qt affine ----------
__global__ __launch_bounds__(256) void attn_fused_kernel(
    const float* __restrict__ qtp, const float* __restrict__ qoffP,
    const float* __restrict__ msumS, const float* __restrict__ m2sumS,
    const float* __restrict__ wqgsum, const float* __restrict__ wqbsum,
    const float* __restrict__ wqS,
    const unsigned short* __restrict__ xnb,
    float* __restrict__ usum, float* __restrict__ denom,
    float* __restrict__ hpp, float* __restrict__ msumN, float* __restrict__ m2sumN) {
    __shared__ __align__(16) unsigned short kv[64][264];   // 64 rows x 256 cols (pitch 264)
    __shared__ float4 qT[264];
    __shared__ float attns[K_][64];
    __shared__ float upd_s[K_][256];
    __shared__ float asw[4][4];
    __shared__ float4 qo_s;
    __shared__ float s_m[4], s_rs[4];

    const int tid = threadIdx.x;
    const int b = blockIdx.y;
    const int chunk = blockIdx.x;
    const int n0 = chunk << 6;
    const int wave = tid >> 6, lane = tid & 63;

    if (tid < 4) {
        float ms = msumS[b * 4 + tid] * (1.f / C_);
        float m2 = m2sumS[b * 4 + tid] * (1.f / C_);
        s_m[tid] = ms;
        s_rs[tid] = rsqrtf(m2 - ms * ms + 1e-5f);
    }
    // housekeeping zero for this iteration's updA accumulation
    if (chunk < 8) hpp[(size_t)(b * 4 + (chunk >> 1)) * HID_ + (chunk & 1) * 256 + tid] = 0.f;
    else if (chunk == 8) {
        if (tid < 4) msumN[b * 4 + tid] = 0.f;
        else if (tid < 8) m2sumN[b * 4 + tid - 4] = 0.f;
    }
    __syncthreads();
    {
        int c = tid;
        float wg = wqgsum[c], wb = wqbsum[c];
        float4 qv;
        qv.x = s_rs[0] * (qtp[(b * 4 + 0) * C_ + c] - s_m[0] * wg) + wb;
        qv.y = s_rs[1] * (qtp[(b * 4 + 1) * C_ + c] - s_m[1] * wg) + wb;
        qv.z = s_rs[2] * (qtp[(b * 4 + 2) * C_ + c] - s_m[2] * wg) + wb;
        qv.w = s_rs[3] * (qtp[(b * 4 + 3) * C_ + c] - s_m[3] * wg) + wb;
        qT[c + (c >> 5)] = qv;
        if (tid == 0) {
            float S1 = wqS[0], S2 = wqS[1];
            float4 qo;
            qo.x = s_rs[0] * (qoffP[b * 4 + 0] - s_m[0] * S1) + S2;
            qo.y = s_rs[1] * (qoffP[b * 4 + 1] - s_m[1] * S1) + S2;
            qo.z = s_rs[2] * (qoffP[b * 4 + 2] - s_m[2] * S1) + S2;
            qo.w = s_rs[3] * (qoffP[b * 4 + 3] - s_m[3] * S1) + S2;
            qo_s = qo;
        }
    }
    __syncthreads();

    // K phase: logits + stage rows into LDS (single global pass over this 64-row tile)
    const int cpart = tid & 7;
    const int npair = tid >> 3;
    const int c0 = cpart << 5;
    float4 acc0 = {0.f, 0.f, 0.f, 0.f}, acc1 = {0.f, 0.f, 0.f, 0.f};
    const unsigned short* kbase = xnb + ((size_t)b * NPIX + n0 + npair * 2) * C_ + c0;
    #pragma unroll
    for (int j = 0; j < 4; ++j) {
        uint4 k0 = *reinterpret_cast<const uint4*>(kbase + j * 8);
        uint4 k1 = *reinterpret_cast<const uint4*>(kbase + C_ + j * 8);
        *reinterpret_cast<uint4*>(&kv[npair * 2][c0 + j * 8]) = k0;
        *reinterpret_cast<uint4*>(&kv[npair * 2 + 1][c0 + j * 8]) = k1;
        const unsigned kw0[4] = {k0.x, k0.y, k0.z, k0.w};
        const unsigned kw1[4] = {k1.x, k1.y, k1.z, k1.w};
        #pragma unroll
        for (int jj = 0; jj < 4; ++jj) {
            int cidx = c0 + j * 8 + jj * 2 + cpart;
            float4 qa = qT[cidx];
            float4 qb = qT[cidx + 1];
            float f00 = bflo(kw0[jj]), f01 = bfhi(kw0[jj]);
            float f10 = bflo(kw1[jj]), f11 = bfhi(kw1[jj]);
            acc0.x += f00 * qa.x + f01 * qb.x;  acc0.y += f00 * qa.y + f01 * qb.y;
            acc0.z += f00 * qa.z + f01 * qb.z;  acc0.w += f00 * qa.w + f01 * qb.w;
            acc1.x += f10 * qa.x + f11 * qb.x;  acc1.y += f10 * qa.y + f11 * qb.y;
            acc1.z += f10 * qa.z + f11 * qb.z;  acc1.w += f10 * qa.w + f11 * qb.w;
        }
    }
    #pragma unroll
    for (int m = 1; m <= 4; m <<= 1) {
        acc0 = acc0 + shfl_xor4(acc0, m);
        acc1 = acc1 + shfl_xor4(acc1, m);
    }
    float4 w0, w1;
    {
        float4 l = (acc0 + qo_s) * 0.0625f;
        float mx = fmaxf(fmaxf(l.x, l.y), fmaxf(l.z, l.w));
        w0.x = expf(l.x - mx); w0.y = expf(l.y - mx);
        w0.z = expf(l.z - mx); w0.w = expf(l.w - mx);
        float inv = 1.0f / (w0.x + w0.y + w0.z + w0.w);
        w0 = w0 * inv;
        l = (acc1 + qo_s) * 0.0625f;
        mx = fmaxf(fmaxf(l.x, l.y), fmaxf(l.z, l.w));
        w1.x = expf(l.x - mx); w1.y = expf(l.y - mx);
        w1.z = expf(l.z - mx); w1.w = expf(l.w - mx);
        inv = 1.0f / (w1.x + w1.y + w1.z + w1.w);
        w1 = w1 * inv;
    }
    if (cpart == 0) {
        int n_l = npair * 2;
        attns[0][n_l] = w0.x; attns[1][n_l] = w0.y; attns[2][n_l] = w0.z; attns[3][n_l] = w0.w;
        attns[0][n_l + 1] = w1.x; attns[1][n_l + 1] = w1.y;
        attns[2][n_l + 1] = w1.z; attns[3][n_l + 1] = w1.w;
    }
    float4 ws = w0 + w1;
    #pragma unroll
    for (int m = 8; m <= 32; m <<= 1) ws = ws + shfl_xor4(ws, m);
    if (lane == 0) {
        asw[wave][0] = ws.x; asw[wave][1] = ws.y; asw[wave][2] = ws.z; asw[wave][3] = ws.w;
    }
    __syncthreads();
    if (tid < 4)
        atomicAdd(&denom[b * 4 + tid],
                  asw[0][tid] + asw[1][tid] + asw[2][tid] + asw[3][tid]);

    // V phase: reads the staged LDS tile (no second global pass)
    const int h = wave >> 1;
    const int chalf = (wave & 1) << 7;
    const int c = chalf + lane * 2;
    float a0[K_] = {0.f, 0.f, 0.f, 0.f};
    float a1[K_] = {0.f, 0.f, 0.f, 0.f};
    #pragma unroll 4
    for (int nn = 0; nn < 32; ++nn) {
        unsigned vv = *reinterpret_cast<const unsigned*>(&kv[h * 32 + nn][c]);
        float v0 = bflo(vv), v1 = bfhi(vv);
        int n_l = h * 32 + nn;
        float q0 = attns[0][n_l], q1 = attns[1][n_l], q2 = attns[2][n_l], q3 = attns[3][n_l];
        a0[0] = fmaf(q0, v0, a0[0]); a1[0] = fmaf(q0, v1, a1[0]);
        a0[1] = fmaf(q1, v0, a0[1]); a1[1] = fmaf(q1, v1, a1[1]);
        a0[2] = fmaf(q2, v0, a0[2]); a1[2] = fmaf(q2, v1, a1[2]);
        a0[3] = fmaf(q3, v0, a0[3]); a1[3] = fmaf(q3, v1, a1[3]);
    }
    __syncthreads();
    if (h == 0) {
        #pragma unroll
        for (int k = 0; k < K_; ++k) { upd_s[k][c] = a0[k]; upd_s[k][c + 1] = a1[k]; }
    }
    __syncthreads();
    if (h == 1) {
        #pragma unroll
        for (int k = 0; k < K_; ++k) { upd_s[k][c] += a0[k]; upd_s[k][c + 1] += a1[k]; }
    }
    __syncthreads();
    #pragma unroll
    for (int k = 0; k < K_; ++k)
        atomicAdd(&usum[((size_t)b * K_ + k) * 256 + tid], upd_s[k][tid]);
}

extern "C" void kernel_launch(void* const* d_in, const int* in_sizes, int n_in,
                              void* d_out, int out_size, void* d_ws, size_t ws_size,
                              hipStream_t stream) {
    (void)in_sizes; (void)n_in; (void)out_size; (void)ws_size;
    const float* x        = (const float*)d_in[0];
    const float* noise    = (const float*)d_in[1];
    const float* slot_mu  = (const float*)d_in[2];
    const float* slot_ls  = (const float*)d_in[3];
    const float* ln_in_g  = (const float*)d_in[4];
    const float* ln_in_b  = (const float*)d_in[5];
    const float* ln_sl_g  = (const float*)d_in[6];
    const float* ln_sl_b  = (const float*)d_in[7];
    const float* ln_mlp_g = (const float*)d_in[8];
    const float* ln_mlp_b = (const float*)d_in[9];
    const float* Wq = (const float*)d_in[10];
    const float* bq = (const float*)d_in[11];
    const float* Wk = (const float*)d_in[12];
    const float* bk = (const float*)d_in[13];
    const float* Wv = (const float*)d_in[14];
    const float* bv = (const float*)d_in[15];
    const float* Wu = (const float*)d_in[16];
    const float* bu = (const float*)d_in[17];
    const float* W1 = (const float*)d_in[18];
    const float* b1 = (const float*)d_in[19];
    const float* W2 = (const float*)d_in[20];
    const float* b2 = (const float*)d_in[21];
    const float* We1 = (const float*)d_in[22];
    const float* be1 = (const float*)d_in[23];
    const float* We2 = (const float*)d_in[24];
    const float* be2 = (const float*)d_in[25];
    float* out = (float*)d_out;

    char* ws = (char*)d_ws;
    unsigned short* xnb = (unsigned short*)ws;                  // 32 MiB
    float4* WuC4  = (float4*)(xnb + (size_t)NROWS * C_);        // 32768 f4
    float4* W24   = WuC4 + 32768;                               // 32768 f4
    float* W1gT   = (float*)(W24 + 32768);                      // 131072
    float* WqgT   = W1gT + 131072;                              // 65536
    float* We1T   = WqgT + 65536;                               // 32768
    float* w1gsum = We1T + 32768;                               // 512
    float* w1bsum = w1gsum + 512;                               // 512
    float* wqgsum = w1bsum + 512;                               // 256
    float* wqbsum = wqgsum + 256;                               // 256
    float* wqg    = wqbsum + 256;                               // 256
    float* wqS    = wqg + 256;                                  // 2 (+pad)
    float* bv2    = wqS + 4;                                    // 256
    float* slots  = bv2 + 256;                                  // 16384
    float* nvbuf  = slots + B_ * K_ * C_;                       // 16384
    float* qtp    = nvbuf + B_ * K_ * C_;                       // 16384
    float* qoffP  = qtp + B_ * K_ * C_;                         // 64
    float* msumS  = qoffP + B_ * K_;                            // 64
    float* m2sumS = msumS + B_ * K_;                            // 64
    float* hpp    = m2sumS + B_ * K_;                           // 32768
    float* msumN  = hpp + B_ * K_ * HID_;                       // 64
    float* m2sumN = msumN + B_ * K_;                            // 64
    float* usum   = m2sumN + B_ * K_;                           // 16384
    float* denom  = usum + B_ * K_ * C_;                        // 64
    float* ep     = denom + B_ * K_;                            // 8192

    prep_all_kernel<<<1091, 256, 0, stream>>>(
        Wu, W1, W2, We1, Wq, Wk, Wv, bk, bq, bv, b1,
        ln_sl_g, ln_sl_b, ln_mlp_g, ln_mlp_b,
        WuC4, W24, W1gT, WqgT, We1T,
        w1gsum, w1bsum, wqgsum, wqbsum, wqg, wqS, bv2);
    xn_fused_kernel<<<dim3(128, 16), 512, 0, stream>>>(x, ln_in_g, ln_in_b, xnb);
    initqt_kernel<<<dim3(2, B_ * K_), 256, 0, stream>>>(
        noise, slot_mu, slot_ls, WqgT, wqg,
        slots, qtp, qoffP, msumS, m2sumS, usum, denom);
    for (int it = 0; it < ITERS_; ++it) {
        const int fin = (it == ITERS_ - 1);
        attn_fused_kernel<<<dim3(64, 16), 256, 0, stream>>>(
            qtp, qoffP, msumS, m2sumS, wqgsum, wqbsum, wqS,
            xnb, usum, denom, hpp, msumN, m2sumN);
        updA_kernel<<<dim3(8, B_ * K_), 256, 0, stream>>>(
            slots, usum, denom, WuC4, bu, bv2, W1gT,
            nvbuf, hpp, msumN, m2sumN, qtp, qoffP, msumS, m2sumS, ep);
        updB_kernel<<<dim3(8, B_ * K_), 256, 0, stream>>>(
            nvbuf, hpp, msumN, m2sumN, w1gsum, w1bsum, W24, b2,
            WqgT, wqg, We1T, fin ? out : slots,
            qtp, qoffP, msumS, m2sumS, ep, usum, denom, fin);
    }
    head_fin_kernel<<<B_ * K_, 128, 0, stream>>>(ep, be1, We2, be2, out);
}